// Round 6
// baseline (474.820 us; speedup 1.0000x reference)
//
#include <hip/hip_runtime.h>
#include <hip/hip_bf16.h>

// Fused MHA forward for MI355X (gfx950).  B=2, S=2048, E=2048, H=16, D=128.
// R5 (resubmit after infra timeout): GEMMs -> 256x256 8-phase template (BK=64,
//     8 waves, 128KB LDS dbuf, XOR-swizzled LDS via pre-swizzled gload_lds
//     source, raw s_barrier, once-per-tile vmcnt(0), setprio around MFMA).
//     Attn unchanged from R4.

typedef __bf16 bf16x8 __attribute__((ext_vector_type(8)));
typedef __bf16 bf16x4 __attribute__((ext_vector_type(4)));
typedef float  f32x4  __attribute__((ext_vector_type(4)));

static __device__ __forceinline__ bf16x8 ld8(const __bf16* p){
  return *reinterpret_cast<const bf16x8*>(p);
}

#define GLOAD_LDS16(gsrc, ldst) \
  __builtin_amdgcn_global_load_lds((const __attribute__((address_space(1))) void*)(gsrc), \
                                   (__attribute__((address_space(3))) void*)(ldst), 16, 0, 0)

static __device__ __forceinline__ unsigned cvtpk(float lo, float hi){
  unsigned r; asm("v_cvt_pk_bf16_f32 %0, %1, %2" : "=v"(r) : "v"(lo), "v"(hi)); return r;
}

// ---------------- fp32 -> bf16 elementwise ----------------
__global__ __launch_bounds__(256) void cvt_kernel(const float* __restrict__ src,
                                                  __bf16* __restrict__ dst, int n4){
  int stride = gridDim.x * blockDim.x;
  for (int i = blockIdx.x*blockDim.x + threadIdx.x; i < n4; i += stride){
    float4 v = reinterpret_cast<const float4*>(src)[i];
    bf16x4 o;
    o[0] = (__bf16)v.x; o[1] = (__bf16)v.y; o[2] = (__bf16)v.z; o[3] = (__bf16)v.w;
    reinterpret_cast<bf16x4*>(dst)[i] = o;
  }
}

// ---------------- fp32 [K][N] -> bf16 [N][K] (transpose + cast) ----------------
__global__ __launch_bounds__(256) void transcvt_kernel(const float* __restrict__ src,
                                                       __bf16* __restrict__ dst,
                                                       int K, int N){
  __shared__ float tile[32][33];
  const int n0 = blockIdx.x*32, k0 = blockIdx.y*32;
  const int tx = threadIdx.x & 31, ty = threadIdx.x >> 5;
  #pragma unroll
  for (int i = 0; i < 32; i += 8)
    tile[ty+i][tx] = src[(size_t)(k0+ty+i)*N + n0 + tx];
  __syncthreads();
  #pragma unroll
  for (int i = 0; i < 32; i += 8)
    dst[(size_t)(n0+ty+i)*K + k0 + tx] = (__bf16)tile[tx][ty+i];
}

// ---------------- 256x256 8-phase bf16 GEMM: C = A[M,K] * Bt[N,K]^T + bias ----
// 512 thr = 8 waves (2 wm x 4 wn); wave tile 128x64; BK=64; 2-deep LDS dbuf.
// LDS layout per buf (64KB): A[256][64] then B[256][64], row-swizzled
// byte ^= (row&7)<<4 (applied via pre-swizzled global source on stage).
// Per K-tile: 4 phases p = M-stripe quadrants; phase = {12 ds_read_b128,
// stage half p of tile jj+1, s_barrier, 16 MFMA (setprio), [p==3: vmcnt(0)],
// s_barrier}.  EPI 0: scatter bf16 q/k/v;  EPI 1: fp32 + bias.
template<int EPI, int NBX>
__global__ __launch_bounds__(512, 2) void gemm256(const __bf16* __restrict__ A,
    const __bf16* __restrict__ Bt, const float* __restrict__ bias,
    __bf16* __restrict__ outb, float* __restrict__ outf, int K, int N)
{
  extern __shared__ char SM[];                   // 131072 B
  const int t = threadIdx.x;
  const int lane = t & 63, wid = t >> 6;
  const int wm = wid >> 2, wn = wid & 3;
  const int g = lane >> 4, lr = lane & 15;
  const int bid = blockIdx.x;
  const int i2 = bid >> 3;
  const int by = (bid & 7)*2 + i2 / NBX;         // 2 m-rows per XCD
  const int bx = i2 % NBX;
  const int m0 = by * 256, n0 = bx * 256;
  const int NT = K >> 6;

  // staging geometry: thread t covers rows srow/srow+64 of a 128-row half
  const int srow = t >> 3;                       // 0..63
  const int scol = 8 * ((t & 7) ^ (srow & 7));   // pre-swizzled source col
  const __bf16* sbase[4];
  sbase[0] = A  + (size_t)(m0 +       srow)*K + scol;
  sbase[1] = A  + (size_t)(m0 + 128 + srow)*K + scol;
  sbase[2] = Bt + (size_t)(n0 +       srow)*K + scol;
  sbase[3] = Bt + (size_t)(n0 + 128 + srow)*K + scol;

  auto stage = [&](int h, int jj){
    const __bf16* s0 = sbase[h] + (size_t)jj*64;
    char* dst = SM + (jj & 1)*65536 + h*16384 + t*16;
    GLOAD_LDS16(s0,                 dst);
    GLOAD_LDS16(s0 + (size_t)64*K,  dst + 8192);
  };

  // prologue: tile 0 fully staged
  #pragma unroll
  for (int h = 0; h < 4; h++) stage(h, 0);
  asm volatile("s_waitcnt vmcnt(0)" ::: "memory");
  __builtin_amdgcn_s_barrier();

  f32x4 acc[8][4] = {};
  const int kswz = (lr & 7) << 4;                // read-side row swizzle

  for (int jj = 0; jj < NT; ++jj){
    const char* base = SM + (jj & 1)*65536;
    #pragma unroll
    for (int p = 0; p < 4; p++){
      bf16x8 af[2][2], bfr[4][2];
      #pragma unroll
      for (int mf = 0; mf < 2; mf++)
        #pragma unroll
        for (int ks = 0; ks < 2; ks++)
          af[mf][ks] = *(const bf16x8*)(base + (wm*128 + p*32 + mf*16 + lr)*128
                                             + ((ks*64 + g*16) ^ kswz));
      #pragma unroll
      for (int nf = 0; nf < 4; nf++)
        #pragma unroll
        for (int ks = 0; ks < 2; ks++)
          bfr[nf][ks] = *(const bf16x8*)(base + 32768 + (wn*64 + nf*16 + lr)*128
                                              + ((ks*64 + g*16) ^ kswz));
      if (jj + 1 < NT) stage(p, jj + 1);
      __builtin_amdgcn_s_barrier();
      __builtin_amdgcn_s_setprio(1);
      #pragma unroll
      for (int ks = 0; ks < 2; ks++)
        #pragma unroll
        for (int mf = 0; mf < 2; mf++)
          #pragma unroll
          for (int nf = 0; nf < 4; nf++)
            acc[p*2+mf][nf] = __builtin_amdgcn_mfma_f32_16x16x32_bf16(
                                af[mf][ks], bfr[nf][ks], acc[p*2+mf][nf], 0,0,0);
      __builtin_amdgcn_s_setprio(0);
      if (p == 3) asm volatile("s_waitcnt vmcnt(0)" ::: "memory");
      __builtin_amdgcn_s_barrier();
    }
  }

  // ---- epilogue: per-wave LDS transpose -> vector stores ----
  __builtin_amdgcn_s_barrier();                  // all LDS reads done; reuse
  float bi[4];
  #pragma unroll
  for (int nf = 0; nf < 4; nf++) bi[nf] = bias[n0 + wn*64 + nf*16 + lr];
  char* EB = SM + wid*2304;                      // [16 rows][144 B]
  const int orow = lane >> 2, oseg = lane & 3;
  #pragma unroll
  for (int i8 = 0; i8 < 8; i8++){
    if (EPI == 0){
      #pragma unroll
      for (int nf = 0; nf < 4; nf++)
        #pragma unroll
        for (int q = 0; q < 4; q++)
          *(__bf16*)(EB + (g*4+q)*144 + (nf*16+lr)*2) = (__bf16)(acc[i8][nf][q] + bi[nf]);
      #pragma unroll
      for (int rnd = 0; rnd < 2; rnd++){
        const int chunk = oseg + rnd*4;          // 8 chunks of 8 bf16
        bf16x8 o8 = *(const bf16x8*)(EB + orow*144 + chunk*16);
        const int gm = m0 + wm*128 + i8*16 + orow;
        const int gn = n0 + wn*64 + chunk*8;
        const int b   = gm >> 11, s = gm & 2047;
        const int sec = gn >> 11, e = gn & 2047;
        const int h   = e >> 7,   d = e & 127;
        *(bf16x8*)&outb[(size_t)sec*8388608u + ((size_t)((b<<4)+h)*2048 + s)*128 + d] = o8;
      }
    } else {
      #pragma unroll
      for (int jh = 0; jh < 2; jh++){
        #pragma unroll
        for (int jl = 0; jl < 2; jl++)
          #pragma unroll
          for (int q = 0; q < 4; q++)
            *(float*)(EB + (g*4+q)*144 + (jl*16+lr)*4) = acc[i8][jh*2+jl][q] + bi[jh*2+jl];
        #pragma unroll
        for (int rnd = 0; rnd < 2; rnd++){
          const int chunk = oseg + rnd*4;        // 8 chunks of 4 f32
          f32x4 o4 = *(const f32x4*)(EB + orow*144 + chunk*16);
          const int gm = m0 + wm*128 + i8*16 + orow;
          const int gn = n0 + wn*64 + jh*32 + chunk*4;
          *(f32x4*)&outf[(size_t)gm*N + gn] = o4;
        }
      }
    }
  }
}

// ---------------- flash attention: 16-q-row waves, KVBLK=32 (R4) ----------------
__global__ __launch_bounds__(256, 4) void attn_kernel(const __bf16* __restrict__ Q,
    const __bf16* __restrict__ Kp, const __bf16* __restrict__ Vp,
    __bf16* __restrict__ O)
{
  __shared__ union {
    struct { __bf16 k[2][32*128]; __bf16 vt[128*32]; } a;  // 16KB + 8KB
    char ot[4*4352];                                       // epilogue [16 q][272 B]
  } sm;
  char* SMB = (char*)&sm;
  const int VT0 = 16384;
  const int t = threadIdx.x, lane = t & 63, w = t >> 6;
  const int l15 = lane & 15, g = lane >> 4;
  const int bid = blockIdx.x;
  const int bh = (bid & 7)*4 + (bid >> 8);   // 4 heads per XCD -> KV L2-resident
  const int qt = (bid >> 3) & 31;
  const int q0 = qt*64 + w*16;
  const __bf16* kbase = Kp + (size_t)bh*2048*128;
  const __bf16* vbase = Vp + (size_t)bh*2048*128;

  const __bf16* qp = Q + ((size_t)bh*2048 + q0 + l15)*128;
  bf16x8 qf[4];
  #pragma unroll
  for (int kc = 0; kc < 4; kc++) qf[kc] = ld8(qp + kc*32 + g*8);

  const int skv = t >> 4, sslot = t & 15;
  const __bf16* ks0 = kbase + (size_t)skv*128 + ((sslot ^ (skv & 15))*8);
  const __bf16* ks1 = ks0 + 16*128;
  const int vkv = lane & 31, vhi = lane >> 5;
  const __bf16* vsrc = vbase + (size_t)vkv*128 + w*32 + vhi*16;
  int vwB[4];
  #pragma unroll
  for (int c = 0; c < 4; c++) vwB[c] = w*2048 + vhi*1024 + ((vkv*2) ^ (c<<4));
  int kaddrB[8];
  #pragma unroll
  for (int h = 0; h < 2; h++){
    const int row = 8*(l15>>2) + 4*h + (l15&3);
    #pragma unroll
    for (int kc = 0; kc < 4; kc++)
      kaddrB[h*4+kc] = row*256 + (((kc*4+g) ^ (row & 15))*16);
  }
  const int vrdB = l15*64 + ((g*16) ^ ((l15&3)<<4));

  f32x4 oacc[8] = {};
  float mrun = -1e30f, lrun = 0.f;
  const float C = 0.127517912f;              // (1/sqrt(128)) * log2(e)

  GLOAD_LDS16(ks0, SMB + t*16);
  GLOAD_LDS16(ks1, SMB + 4096 + t*16);
  bf16x8 vr0 = ld8(vsrc), vr1 = ld8(vsrc + 8);

  auto tile = [&](int TT, int BUF, int NBUF){
    __syncthreads();
    #pragma unroll
    for (int e = 0; e < 8; e++)
      *(__bf16*)(SMB + VT0 + vwB[e&3] + e*64) = vr0[e];
    #pragma unroll
    for (int e = 0; e < 8; e++)
      *(__bf16*)(SMB + VT0 + vwB[e&3] + (8+e)*64) = vr1[e];
    __syncthreads();
    if (TT < 63){
      const size_t kvn = (size_t)(TT+1)*32;
      GLOAD_LDS16(ks0 + kvn*128, SMB + NBUF*8192 + t*16);
      GLOAD_LDS16(ks1 + kvn*128, SMB + NBUF*8192 + 4096 + t*16);
      vr0 = ld8(vsrc + kvn*128);
      vr1 = ld8(vsrc + kvn*128 + 8);
    }
    f32x4 s0 = {}, s1 = {};
    #pragma unroll
    for (int kc = 0; kc < 4; kc++){
      bf16x8 k0 = *(const bf16x8*)(SMB + BUF*8192 + kaddrB[kc]);
      bf16x8 k1 = *(const bf16x8*)(SMB + BUF*8192 + kaddrB[4+kc]);
      s0 = __builtin_amdgcn_mfma_f32_16x16x32_bf16(k0, qf[kc], s0, 0,0,0);
      s1 = __builtin_amdgcn_mfma_f32_16x16x32_bf16(k1, qf[kc], s1, 0,0,0);
    }
    float pm = fmaxf(fmaxf(fmaxf(s0[0],s0[1]),fmaxf(s0[2],s0[3])),
                     fmaxf(fmaxf(s1[0],s1[1]),fmaxf(s1[2],s1[3])));
    pm = fmaxf(pm, __shfl_xor(pm, 16));
    pm = fmaxf(pm, __shfl_xor(pm, 32));
    if (!__all(pm <= mrun + 90.51f)){
      float mnew = fmaxf(mrun, pm);
      float al = exp2f((mrun - mnew)*C);
      mrun = mnew; lrun *= al;
      #pragma unroll
      for (int d = 0; d < 8; d++) oacc[d] *= al;
    }
    float pp[8];
    #pragma unroll
    for (int r = 0; r < 4; r++){
      pp[r]   = exp2f((s0[r] - mrun)*C);
      pp[4+r] = exp2f((s1[r] - mrun)*C);
    }
    float ls = ((pp[0]+pp[1])+(pp[2]+pp[3])) + ((pp[4]+pp[5])+(pp[6]+pp[7]));
    ls += __shfl_xor(ls, 16);
    ls += __shfl_xor(ls, 32);
    lrun += ls;
    union { unsigned u[4]; bf16x8 v; } pw;
    pw.u[0] = cvtpk(pp[0], pp[1]);
    pw.u[1] = cvtpk(pp[2], pp[3]);
    pw.u[2] = cvtpk(pp[4], pp[5]);
    pw.u[3] = cvtpk(pp[6], pp[7]);
    #pragma unroll
    for (int d0 = 0; d0 < 8; d0++){
      bf16x8 vf = *(const bf16x8*)(SMB + VT0 + vrdB + d0*1024);
      oacc[d0] = __builtin_amdgcn_mfma_f32_16x16x32_bf16(vf, pw.v, oacc[d0], 0,0,0);
    }
  };

  for (int it = 0; it < 32; ++it){
    tile(2*it,   0, 1);
    tile(2*it+1, 1, 0);
  }

  __syncthreads();
  const float invl = 1.0f / lrun;
  #pragma unroll
  for (int d0 = 0; d0 < 8; d0++){
    bf16x4 o4;
    #pragma unroll
    for (int r = 0; r < 4; r++) o4[r] = (__bf16)(oacc[d0][r]*invl);
    *(bf16x4*)(SMB + w*4352 + l15*272 + d0*32 + g*8) = o4;
  }
  const int b = bh >> 4, h = bh & 15;
  const int orow = lane >> 2, oseg = lane & 3;
  #pragma unroll
  for (int itc = 0; itc < 4; itc++){
    const int chunk = oseg + itc*4;
    bf16x8 o8 = *(const bf16x8*)(SMB + w*4352 + orow*272 + chunk*16);
    *(bf16x8*)&O[((size_t)(b*2048 + q0 + orow))*2048 + h*128 + chunk*8] = o8;
  }
}

extern "C" void kernel_launch(void* const* d_in, const int* in_sizes, int n_in,
                              void* d_out, int out_size, void* d_ws, size_t ws_size,
                              hipStream_t stream) {
  const float* x     = (const float*)d_in[0];
  const float* Wqkv  = (const float*)d_in[1];
  const float* bqkv  = (const float*)d_in[2];
  const float* Wproj = (const float*)d_in[3];
  const float* bproj = (const float*)d_in[4];
  float* out = (float*)d_out;

  __bf16* xb     = (__bf16*)d_ws;                       // [4096][2048]
  __bf16* wqkvT  = xb     + (size_t)4096*2048;          // [6144][2048]
  __bf16* wprojT = wqkvT  + (size_t)6144*2048;          // [2048][2048]
  __bf16* qq     = wprojT + (size_t)2048*2048;          // [32][2048][128]
  __bf16* kk     = qq     + (size_t)32*2048*128;
  __bf16* vv     = kk     + (size_t)32*2048*128;
  __bf16* attb   = vv     + (size_t)32*2048*128;        // [4096][2048]

  hipFuncSetAttribute(reinterpret_cast<const void*>(gemm256<0,24>),
                      hipFuncAttributeMaxDynamicSharedMemorySize, 131072);
  hipFuncSetAttribute(reinterpret_cast<const void*>(gemm256<1,8>),
                      hipFuncAttributeMaxDynamicSharedMemorySize, 131072);

  cvt_kernel<<<2048, 256, 0, stream>>>(x, xb, (4096*2048)/4);
  transcvt_kernel<<<dim3(6144/32, 2048/32), 256, 0, stream>>>(Wqkv, wqkvT, 2048, 6144);
  transcvt_kernel<<<dim3(2048/32, 2048/32), 256, 0, stream>>>(Wproj, wprojT, 2048, 2048);
  gemm256<0,24><<<384, 512, 131072, stream>>>(xb, wqkvT, bqkv, qq, nullptr, 2048, 6144);
  attn_kernel<<<1024, 256, 0, stream>>>(qq, kk, vv, attb);
  gemm256<1,8><<<128, 512, 131072, stream>>>(attb, wprojT, bproj, nullptr, out, 2048, 2048);
}

// Round 8
// 407.983 us; speedup vs baseline: 1.1638x; 1.1638x over previous
//
#include <hip/hip_runtime.h>
#include <hip/hip_bf16.h>

// Fused MHA forward for MI355X (gfx950).  B=2, S=2048, E=2048, H=16, D=128.
// R7 (resubmit after infra timeout): GEMMs -> per-wave-ownership pipeline:
//     each wave stages ONLY the LDS chunks it consumes (A-half(wm), B-half
//     group) so its own vmcnt(0) is a precise counted wait; loads issue a
//     full K-tile ahead; ONE barrier per K-tile; verified XOR-swizzle pair
//     kept. G2 grid fixed to 256 blocks (BN=128). Attn unchanged (R4).

typedef __bf16 bf16x8 __attribute__((ext_vector_type(8)));
typedef __bf16 bf16x4 __attribute__((ext_vector_type(4)));
typedef float  f32x4  __attribute__((ext_vector_type(4)));

static __device__ __forceinline__ bf16x8 ld8(const __bf16* p){
  return *reinterpret_cast<const bf16x8*>(p);
}

#define GLOAD_LDS16(gsrc, ldst) \
  __builtin_amdgcn_global_load_lds((const __attribute__((address_space(1))) void*)(gsrc), \
                                   (__attribute__((address_space(3))) void*)(ldst), 16, 0, 0)

static __device__ __forceinline__ unsigned cvtpk(float lo, float hi){
  unsigned r; asm("v_cvt_pk_bf16_f32 %0, %1, %2" : "=v"(r) : "v"(lo), "v"(hi)); return r;
}

// ---------------- fp32 -> bf16 elementwise ----------------
__global__ __launch_bounds__(256) void cvt_kernel(const float* __restrict__ src,
                                                  __bf16* __restrict__ dst, int n4){
  int stride = gridDim.x * blockDim.x;
  for (int i = blockIdx.x*blockDim.x + threadIdx.x; i < n4; i += stride){
    float4 v = reinterpret_cast<const float4*>(src)[i];
    bf16x4 o;
    o[0] = (__bf16)v.x; o[1] = (__bf16)v.y; o[2] = (__bf16)v.z; o[3] = (__bf16)v.w;
    reinterpret_cast<bf16x4*>(dst)[i] = o;
  }
}

// ---------------- fp32 [K][N] -> bf16 [N][K] (transpose + cast) ----------------
__global__ __launch_bounds__(256) void transcvt_kernel(const float* __restrict__ src,
                                                       __bf16* __restrict__ dst,
                                                       int K, int N){
  __shared__ float tile[32][33];
  const int n0 = blockIdx.x*32, k0 = blockIdx.y*32;
  const int tx = threadIdx.x & 31, ty = threadIdx.x >> 5;
  #pragma unroll
  for (int i = 0; i < 32; i += 8)
    tile[ty+i][tx] = src[(size_t)(k0+ty+i)*N + n0 + tx];
  __syncthreads();
  #pragma unroll
  for (int i = 0; i < 32; i += 8)
    dst[(size_t)(n0+ty+i)*K + k0 + tx] = (__bf16)tile[tx][ty+i];
}

// ---------------- 256xBN bf16 GEMM: C = A[M,K] * Bt[N,K]^T + bias ----------
// BM=256 fixed. 512 thr = 8 waves (WM x WN); wave tile (256/WM)x(BN/WN).
// BK=64, 2-deep LDS dbuf. Per buf: A[256][64] @0, B[BN][64] @32768,
// row-swizzled byte ^= (row&7)<<4 via pre-swizzled global source (R5-verified).
// OWNERSHIP: wave (wm,wn) stages only A rows [ha*128+qa*32,+32) and B rows
// [hb*BH+qb*BH/4,+BH/4) -- exactly the halves it reads. Its own vmcnt(0)
// (issued at top of previous tile body) is the counted wait; ONE s_barrier
// per K-tile publishes LDS.  EPI 0: bf16 scatter to q/k/v; EPI 1: fp32+bias.
template<int EPI, int NBX, int WM, int WN, int BN>
__global__ __launch_bounds__(512, 2) void gemm256(const __bf16* __restrict__ A,
    const __bf16* __restrict__ Bt, const float* __restrict__ bias,
    __bf16* __restrict__ outb, float* __restrict__ outf, int K, int N)
{
  extern __shared__ char SM[];
  constexpr int TM  = 256 / WM;            // wave tile M
  constexpr int TN  = BN  / WN;            // wave tile N
  constexpr int MF  = TM / 16;
  constexpr int NF  = TN / 16;
  constexpr int BH  = BN / 2;              // B half rows
  constexpr int NBL = BH / 32;             // B stage loads per lane
  constexpr int BUFB = 32768 + BN*128;     // bytes per buffer

  const int t = threadIdx.x;
  const int lane = t & 63, wid = t >> 6;
  const int wm = wid / WN, wn = wid % WN;
  const int g = lane >> 4, lr = lane & 15;
  const int bid = blockIdx.x;
  const int i2 = bid >> 3;
  const int by = (bid & 7)*2 + i2 / NBX;   // 2 m-rows per XCD
  const int bx = i2 % NBX;
  const int m0 = by * 256, n0 = bx * BN;
  const int NT = K >> 6;

  // ---- ownership: which chunks this wave stages ----
  const int ha = wm / (WM/2);
  const int qa = (wm % (WM/2)) * WN + wn;          // 0..3
  const int r0a = ha*128 + qa*32;
  const int hb = wn / ((WN/2) ? (WN/2) : 1);
  const int qb = wm * (WN/2) + (wn % ((WN/2) ? (WN/2) : 1));   // 0..3
  const int r0b = hb*BH + qb*(BH/4);

  // per-lane source pointers (pre-swizzled col) and linear LDS dests
  const __bf16* aSrc[4]; const __bf16* bSrc[4];
  #pragma unroll
  for (int i = 0; i < 4; i++){
    const int s = i*64 + lane;
    const int row = r0a + (s >> 3);
    const int col = ((s & 7) ^ ((s >> 3) & 7)) * 8;
    aSrc[i] = A + (size_t)(m0 + row)*K + col;
  }
  #pragma unroll
  for (int i = 0; i < NBL; i++){
    const int s = i*64 + lane;
    const int row = r0b + (s >> 3);
    const int col = ((s & 7) ^ ((s >> 3) & 7)) * 8;
    bSrc[i] = Bt + (size_t)(n0 + row)*K + col;
  }

  auto stage = [&](int jj){
    char* bufb = SM + (jj & 1)*BUFB;
    char* da = bufb + r0a*128 + lane*16;
    char* db = bufb + 32768 + r0b*128 + lane*16;
    const size_t ko = (size_t)jj * 64;
    #pragma unroll
    for (int i = 0; i < 4; i++)   GLOAD_LDS16(aSrc[i] + ko, da + i*1024);
    #pragma unroll
    for (int i = 0; i < NBL; i++) GLOAD_LDS16(bSrc[i] + ko, db + i*1024);
  };

  // prologue: tile 0
  stage(0);
  asm volatile("s_waitcnt vmcnt(0)" ::: "memory");
  __builtin_amdgcn_s_barrier();

  f32x4 acc[MF][NF] = {};
  const int kswz = (lr & 7) << 4;

  for (int jj = 0; jj < NT; ++jj){
    if (jj + 1 < NT) stage(jj + 1);          // issue early: full tile of cover
    __builtin_amdgcn_sched_barrier(0);       // pin issues before compute
    const char* base = SM + (jj & 1)*BUFB;
    #pragma unroll
    for (int ks = 0; ks < 2; ks++){
      bf16x8 af[MF], bfr[NF];
      #pragma unroll
      for (int mf = 0; mf < MF; mf++)
        af[mf] = *(const bf16x8*)(base + (wm*TM + mf*16 + lr)*128
                                       + ((ks*64 + g*16) ^ kswz));
      #pragma unroll
      for (int nf = 0; nf < NF; nf++)
        bfr[nf] = *(const bf16x8*)(base + 32768 + (wn*TN + nf*16 + lr)*128
                                        + ((ks*64 + g*16) ^ kswz));
      __builtin_amdgcn_s_setprio(1);
      #pragma unroll
      for (int mf = 0; mf < MF; mf++)
        #pragma unroll
        for (int nf = 0; nf < NF; nf++)
          acc[mf][nf] = __builtin_amdgcn_mfma_f32_16x16x32_bf16(
                          af[mf], bfr[nf], acc[mf][nf], 0,0,0);
      __builtin_amdgcn_s_setprio(0);
    }
    asm volatile("s_waitcnt vmcnt(0)" ::: "memory");  // own chunks for jj+1 landed
    __builtin_amdgcn_s_barrier();                     // publish to consumers
  }

  // ---- epilogue: per-wave LDS transpose -> vector stores ----
  float bi[NF];
  #pragma unroll
  for (int nf = 0; nf < NF; nf++) bi[nf] = bias[n0 + wn*TN + nf*16 + lr];
  char* EB = SM + wid*2304;                      // [16 rows][144 B]
  const int orow = lane >> 2, oseg = lane & 3;
  #pragma unroll
  for (int i8 = 0; i8 < MF; i8++){
    if (EPI == 0){
      #pragma unroll
      for (int nf = 0; nf < NF; nf++)
        #pragma unroll
        for (int q = 0; q < 4; q++)
          *(__bf16*)(EB + (g*4+q)*144 + (nf*16+lr)*2) = (__bf16)(acc[i8][nf][q] + bi[nf]);
      __builtin_amdgcn_s_waitcnt(0);
      #pragma unroll
      for (int rnd = 0; rnd < 2; rnd++){
        const int chunk = oseg + rnd*4;          // 8 chunks of 8 bf16
        bf16x8 o8 = *(const bf16x8*)(EB + orow*144 + chunk*16);
        const int gm = m0 + wm*TM + i8*16 + orow;
        const int gn = n0 + wn*TN + chunk*8;
        const int b   = gm >> 11, s = gm & 2047;
        const int sec = gn >> 11, e = gn & 2047;
        const int h   = e >> 7,   d = e & 127;
        *(bf16x8*)&outb[(size_t)sec*8388608u + ((size_t)((b<<4)+h)*2048 + s)*128 + d] = o8;
      }
      __builtin_amdgcn_s_waitcnt(0);
    } else {
      #pragma unroll
      for (int jh = 0; jh < NF/2; jh++){
        #pragma unroll
        for (int jl = 0; jl < 2; jl++)
          #pragma unroll
          for (int q = 0; q < 4; q++)
            *(float*)(EB + (g*4+q)*144 + (jl*16+lr)*4) = acc[i8][jh*2+jl][q] + bi[jh*2+jl];
        __builtin_amdgcn_s_waitcnt(0);
        #pragma unroll
        for (int rnd = 0; rnd < 2; rnd++){
          const int chunk = oseg + rnd*4;        // 8 chunks of 4 f32
          f32x4 o4 = *(const f32x4*)(EB + orow*144 + chunk*16);
          const int gm = m0 + wm*TM + i8*16 + orow;
          const int gn = n0 + wn*TN + jh*32 + chunk*4;
          *(f32x4*)&outf[(size_t)gm*N + gn] = o4;
        }
        __builtin_amdgcn_s_waitcnt(0);
      }
    }
  }
}

// ---------------- flash attention: 16-q-row waves, KVBLK=32 (R4) ----------------
__global__ __launch_bounds__(256, 4) void attn_kernel(const __bf16* __restrict__ Q,
    const __bf16* __restrict__ Kp, const __bf16* __restrict__ Vp,
    __bf16* __restrict__ O)
{
  __shared__ union {
    struct { __bf16 k[2][32*128]; __bf16 vt[128*32]; } a;  // 16KB + 8KB
    char ot[4*4352];                                       // epilogue [16 q][272 B]
  } sm;
  char* SMB = (char*)&sm;
  const int VT0 = 16384;
  const int t = threadIdx.x, lane = t & 63, w = t >> 6;
  const int l15 = lane & 15, g = lane >> 4;
  const int bid = blockIdx.x;
  const int bh = (bid & 7)*4 + (bid >> 8);   // 4 heads per XCD -> KV L2-resident
  const int qt = (bid >> 3) & 31;
  const int q0 = qt*64 + w*16;
  const __bf16* kbase = Kp + (size_t)bh*2048*128;
  const __bf16* vbase = Vp + (size_t)bh*2048*128;

  const __bf16* qp = Q + ((size_t)bh*2048 + q0 + l15)*128;
  bf16x8 qf[4];
  #pragma unroll
  for (int kc = 0; kc < 4; kc++) qf[kc] = ld8(qp + kc*32 + g*8);

  const int skv = t >> 4, sslot = t & 15;
  const __bf16* ks0 = kbase + (size_t)skv*128 + ((sslot ^ (skv & 15))*8);
  const __bf16* ks1 = ks0 + 16*128;
  const int vkv = lane & 31, vhi = lane >> 5;
  const __bf16* vsrc = vbase + (size_t)vkv*128 + w*32 + vhi*16;
  int vwB[4];
  #pragma unroll
  for (int c = 0; c < 4; c++) vwB[c] = w*2048 + vhi*1024 + ((vkv*2) ^ (c<<4));
  int kaddrB[8];
  #pragma unroll
  for (int h = 0; h < 2; h++){
    const int row = 8*(l15>>2) + 4*h + (l15&3);
    #pragma unroll
    for (int kc = 0; kc < 4; kc++)
      kaddrB[h*4+kc] = row*256 + (((kc*4+g) ^ (row & 15))*16);
  }
  const int vrdB = l15*64 + ((g*16) ^ ((l15&3)<<4));

  f32x4 oacc[8] = {};
  float mrun = -1e30f, lrun = 0.f;
  const float C = 0.127517912f;              // (1/sqrt(128)) * log2(e)

  GLOAD_LDS16(ks0, SMB + t*16);
  GLOAD_LDS16(ks1, SMB + 4096 + t*16);
  bf16x8 vr0 = ld8(vsrc), vr1 = ld8(vsrc + 8);

  auto tile = [&](int TT, int BUF, int NBUF){
    __syncthreads();
    #pragma unroll
    for (int e = 0; e < 8; e++)
      *(__bf16*)(SMB + VT0 + vwB[e&3] + e*64) = vr0[e];
    #pragma unroll
    for (int e = 0; e < 8; e++)
      *(__bf16*)(SMB + VT0 + vwB[e&3] + (8+e)*64) = vr1[e];
    __syncthreads();
    if (TT < 63){
      const size_t kvn = (size_t)(TT+1)*32;
      GLOAD_LDS16(ks0 + kvn*128, SMB + NBUF*8192 + t*16);
      GLOAD_LDS16(ks1 + kvn*128, SMB + NBUF*8192 + 4096 + t*16);
      vr0 = ld8(vsrc + kvn*128);
      vr1 = ld8(vsrc + kvn*128 + 8);
    }
    f32x4 s0 = {}, s1 = {};
    #pragma unroll
    for (int kc = 0; kc < 4; kc++){
      bf16x8 k0 = *(const bf16x8*)(SMB + BUF*8192 + kaddrB[kc]);
      bf16x8 k1 = *(const bf16x8*)(SMB + BUF*8192 + kaddrB[4+kc]);
      s0 = __builtin_amdgcn_mfma_f32_16x16x32_bf16(k0, qf[kc], s0, 0,0,0);
      s1 = __builtin_amdgcn_mfma_f32_16x16x32_bf16(k1, qf[kc], s1, 0,0,0);
    }
    float pm = fmaxf(fmaxf(fmaxf(s0[0],s0[1]),fmaxf(s0[2],s0[3])),
                     fmaxf(fmaxf(s1[0],s1[1]),fmaxf(s1[2],s1[3])));
    pm = fmaxf(pm, __shfl_xor(pm, 16));
    pm = fmaxf(pm, __shfl_xor(pm, 32));
    if (!__all(pm <= mrun + 90.51f)){
      float mnew = fmaxf(mrun, pm);
      float al = exp2f((mrun - mnew)*C);
      mrun = mnew; lrun *= al;
      #pragma unroll
      for (int d = 0; d < 8; d++) oacc[d] *= al;
    }
    float pp[8];
    #pragma unroll
    for (int r = 0; r < 4; r++){
      pp[r]   = exp2f((s0[r] - mrun)*C);
      pp[4+r] = exp2f((s1[r] - mrun)*C);
    }
    float ls = ((pp[0]+pp[1])+(pp[2]+pp[3])) + ((pp[4]+pp[5])+(pp[6]+pp[7]));
    ls += __shfl_xor(ls, 16);
    ls += __shfl_xor(ls, 32);
    lrun += ls;
    union { unsigned u[4]; bf16x8 v; } pw;
    pw.u[0] = cvtpk(pp[0], pp[1]);
    pw.u[1] = cvtpk(pp[2], pp[3]);
    pw.u[2] = cvtpk(pp[4], pp[5]);
    pw.u[3] = cvtpk(pp[6], pp[7]);
    #pragma unroll
    for (int d0 = 0; d0 < 8; d0++){
      bf16x8 vf = *(const bf16x8*)(SMB + VT0 + vrdB + d0*1024);
      oacc[d0] = __builtin_amdgcn_mfma_f32_16x16x32_bf16(vf, pw.v, oacc[d0], 0,0,0);
    }
  };

  for (int it = 0; it < 32; ++it){
    tile(2*it,   0, 1);
    tile(2*it+1, 1, 0);
  }

  __syncthreads();
  const float invl = 1.0f / lrun;
  #pragma unroll
  for (int d0 = 0; d0 < 8; d0++){
    bf16x4 o4;
    #pragma unroll
    for (int r = 0; r < 4; r++) o4[r] = (__bf16)(oacc[d0][r]*invl);
    *(bf16x4*)(SMB + w*4352 + l15*272 + d0*32 + g*8) = o4;
  }
  const int b = bh >> 4, h = bh & 15;
  const int orow = lane >> 2, oseg = lane & 3;
  #pragma unroll
  for (int itc = 0; itc < 4; itc++){
    const int chunk = oseg + itc*4;
    bf16x8 o8 = *(const bf16x8*)(SMB + w*4352 + orow*272 + chunk*16);
    *(bf16x8*)&O[((size_t)(b*2048 + q0 + orow))*2048 + h*128 + chunk*8] = o8;
  }
}

extern "C" void kernel_launch(void* const* d_in, const int* in_sizes, int n_in,
                              void* d_out, int out_size, void* d_ws, size_t ws_size,
                              hipStream_t stream) {
  const float* x     = (const float*)d_in[0];
  const float* Wqkv  = (const float*)d_in[1];
  const float* bqkv  = (const float*)d_in[2];
  const float* Wproj = (const float*)d_in[3];
  const float* bproj = (const float*)d_in[4];
  float* out = (float*)d_out;

  __bf16* xb     = (__bf16*)d_ws;                       // [4096][2048]
  __bf16* wqkvT  = xb     + (size_t)4096*2048;          // [6144][2048]
  __bf16* wprojT = wqkvT  + (size_t)6144*2048;          // [2048][2048]
  __bf16* qq     = wprojT + (size_t)2048*2048;          // [32][2048][128]
  __bf16* kk     = qq     + (size_t)32*2048*128;
  __bf16* vv     = kk     + (size_t)32*2048*128;
  __bf16* attb   = vv     + (size_t)32*2048*128;        // [4096][2048]

  hipFuncSetAttribute(reinterpret_cast<const void*>(gemm256<0,24,2,4,256>),
                      hipFuncAttributeMaxDynamicSharedMemorySize, 131072);
  hipFuncSetAttribute(reinterpret_cast<const void*>(gemm256<1,16,4,2,128>),
                      hipFuncAttributeMaxDynamicSharedMemorySize, 98304);

  cvt_kernel<<<2048, 256, 0, stream>>>(x, xb, (4096*2048)/4);
  transcvt_kernel<<<dim3(6144/32, 2048/32), 256, 0, stream>>>(Wqkv, wqkvT, 2048, 6144);
  transcvt_kernel<<<dim3(2048/32, 2048/32), 256, 0, stream>>>(Wproj, wprojT, 2048, 2048);
  gemm256<0,24,2,4,256><<<384, 512, 131072, stream>>>(xb, wqkvT, bqkv, qq, nullptr, 2048, 6144);
  attn_kernel<<<1024, 256, 0, stream>>>(qq, kk, vv, attb);
  gemm256<1,16,4,2,128><<<256, 512, 98304, stream>>>(attb, wprojT, bproj, nullptr, out, 2048, 2048);
}